// Round 1
// 286.667 us; speedup vs baseline: 1.0804x; 1.0804x over previous
//
#include <hip/hip_runtime.h>
#include <hip/hip_bf16.h>
#include <stdint.h>

#define B_ROWS 16384
#define D_K    2048
#define C_COLS 1000
#define C_PAD  1024
#define EPS_D2 1e-12f

// GEMM geometry: 256x256 tile, BK=32, 8 waves (2M x 4N), 4-deep LDS ring.
#define BM 256
#define BN 256
#define BK 32
#define NT (D_K / BK)          // 64 K-tiles
#define BUF_BYTES 32768        // A 16K + B 16K per K-tile
#define NBUF 4                 // ring depth (128 KiB LDS total)

typedef __attribute__((ext_vector_type(8))) short bf16x8;
typedef __attribute__((ext_vector_type(4))) float f32x4;

__device__ __forceinline__ void async16(void* lds, const void* g) {
    __builtin_amdgcn_global_load_lds(
        (const __attribute__((address_space(1))) unsigned int*)g,
        (__attribute__((address_space(3))) unsigned int*)lds,
        16, 0, 0);
}

// 4 f32 -> 4 bf16 (RNE) packed into uint2
__device__ __forceinline__ uint2 pack_bf16x4(float4 v) {
    union { __hip_bfloat162 h; uint32_t u; } a, b;
    a.h = __float22bfloat162_rn(make_float2(v.x, v.y));
    b.h = __float22bfloat162_rn(make_float2(v.z, v.w));
    uint2 r; r.x = a.u; r.y = b.u; return r;
}

// Wave-per-row prep: fp32 -> bf16 (RNE) + fp32 sum-of-squares. (unchanged)
__global__ __launch_bounds__(256) void prep_all(
    const float* __restrict__ x, const float* __restrict__ w,
    __hip_bfloat16* __restrict__ xb, __hip_bfloat16* __restrict__ wb,
    float* __restrict__ x2, float* __restrict__ w2) {
    const int t = threadIdx.x;
    const int wave = t >> 6;
    const int lane = t & 63;
    const int row = blockIdx.x * 4 + wave;

    const float* src;
    uint4* dst;
    float* norm_out;
    bool valid;
    if (row < B_ROWS) {
        src = x + (size_t)row * D_K;
        dst = (uint4*)(xb + (size_t)row * D_K);
        norm_out = x2 + row;
        valid = true;
    } else {
        int c = row - B_ROWS;
        src = w + (size_t)c * D_K;
        dst = (uint4*)(wb + (size_t)c * D_K);
        norm_out = w2 + c;
        valid = (c < C_COLS);
    }

    float4 v[8];
    if (valid) {
        const float4* s4 = (const float4*)src;
        #pragma unroll
        for (int i = 0; i < 4; i++) {
            v[2 * i]     = s4[2 * lane + 128 * i];
            v[2 * i + 1] = s4[2 * lane + 1 + 128 * i];
        }
    } else {
        #pragma unroll
        for (int i = 0; i < 8; i++) v[i] = make_float4(0.f, 0.f, 0.f, 0.f);
    }

    float ss = 0.f;
    #pragma unroll
    for (int i = 0; i < 8; i++)
        ss += v[i].x * v[i].x + v[i].y * v[i].y + v[i].z * v[i].z + v[i].w * v[i].w;

    #pragma unroll
    for (int i = 0; i < 4; i++) {
        uint2 a = pack_bf16x4(v[2 * i]);
        uint2 b = pack_bf16x4(v[2 * i + 1]);
        uint4 p; p.x = a.x; p.y = a.y; p.z = b.x; p.w = b.y;
        dst[lane + 64 * i] = p;
    }

    #pragma unroll
    for (int off = 32; off > 0; off >>= 1) ss += __shfl_down(ss, off, 64);
    if (lane == 0 && valid) *norm_out = ss;
}

// 256x256 tile, BK=32, 512 threads = 8 waves (2Mx4N), wave tile 128x64.
// 4-deep LDS ring, distance-3 global_load_lds prefetch, ONE s_barrier +
// counted vmcnt(8) per K-tile (T3+T4), setprio around MFMA clusters (T5),
// XOR chunk swizzle (conflict-free ds_read_b128), direct coalesced epilogue.
__global__ __launch_bounds__(512, 2) void dml_gemm(
    const __hip_bfloat16* __restrict__ A,   // [B_ROWS, D_K] bf16
    const __hip_bfloat16* __restrict__ Bm,  // [C_PAD, D_K] bf16 (padded)
    const float* __restrict__ x2, const float* __restrict__ w2,
    const float* __restrict__ scales, float* __restrict__ out)
{
    __shared__ __align__(16) char smem[NBUF * BUF_BYTES];   // 131072 B

    const int tid  = threadIdx.x;
    const int wave = tid >> 6;
    const int lane = tid & 63;
    const int wm = wave >> 2;     // 0..1
    const int wn = wave & 3;      // 0..3

    // XCD-chunked mapping: 256 blocks = 1/CU; XCD x owns m-tiles [8x, 8x+8) x all 4 n.
    const int id  = blockIdx.x;
    const int xcd = id & 7;
    const int j5  = id >> 3;
    const int m0  = (xcd * 8 + (j5 & 7)) * BM;
    const int n0  = (j5 >> 3) * BN;

    // ---- staging geometry: 1024 16B-chunks per operand per K-tile; 2 per thread.
    // chunk L: row r = L>>2, stored pos c = L&3 holds global k-chunk g = c ^ ((r>>1)&3)
    // (linear LDS dest, inverse-swizzled global source; read applies same XOR)
    const int L0 = tid, L1 = tid + 512;
    const int r0 = L0 >> 2, g0 = (L0 & 3) ^ ((r0 >> 1) & 3);
    const int r1 = L1 >> 2, g1 = (L1 & 3) ^ ((r1 >> 1) & 3);
    const __hip_bfloat16* pA0 = A  + (size_t)(m0 + r0) * D_K + g0 * 8;
    const __hip_bfloat16* pA1 = A  + (size_t)(m0 + r1) * D_K + g1 * 8;
    const __hip_bfloat16* pB0 = Bm + (size_t)(n0 + r0) * D_K + g0 * 8;
    const __hip_bfloat16* pB1 = Bm + (size_t)(n0 + r1) * D_K + g1 * 8;
    char* ldA0 = smem + L0 * 16;
    char* ldA1 = smem + L1 * 16;
    char* ldB0 = smem + 16384 + L0 * 16;
    char* ldB1 = smem + 16384 + L1 * 16;

    // ---- fragment read ptrs (row = 64 B, 4 chunks; swizzled chunk = fq ^ ((fr>>1)&3))
    const int fr = lane & 15;
    const int fq = lane >> 4;
    const int ksw = (fq ^ ((fr >> 1) & 3)) * 16;
    const char* fA = smem + (wm * 128 + fr) * 64 + ksw;
    const char* fB = smem + 16384 + (wn * 64 + fr) * 64 + ksw;

    f32x4 acc[8][4] = {};

    // ---- prologue: stage K-tiles 0..2 (12 loads/thread), retire tile 0, barrier.
    #pragma unroll
    for (int tgt = 0; tgt < 3; ++tgt) {
        const int sbo = tgt * BUF_BYTES;
        async16(ldA0 + sbo, pA0 + tgt * BK);
        async16(ldA1 + sbo, pA1 + tgt * BK);
        async16(ldB0 + sbo, pB0 + tgt * BK);
        async16(ldB1 + sbo, pB1 + tgt * BK);
    }
    asm volatile("s_waitcnt vmcnt(8)" ::: "memory");
    __builtin_amdgcn_s_barrier();
    __builtin_amdgcn_sched_barrier(0);

    // ---- main loop: tile t reads buf[t&3], stages tile t+3 into buf[(t+3)&3].
    #pragma unroll 1
    for (int t = 0; t < NT; ++t) {
        const int bo  = (t & 3) * BUF_BYTES;
        const int tgt = t + 3;
        const bool do_stage = (tgt < NT);
        const int sbo = (tgt & 3) * BUF_BYTES;

        // phase 1: issue A-prefetch; read B frags (reused both phases) + A frags mh=0
        if (do_stage) {
            async16(ldA0 + sbo, pA0 + tgt * BK);
            async16(ldA1 + sbo, pA1 + tgt * BK);
        }
        bf16x8 b[4], a[4];
        #pragma unroll
        for (int q = 0; q < 4; ++q) b[q] = *(const bf16x8*)(fB + bo + q * 1024);
        #pragma unroll
        for (int i = 0; i < 4; ++i) a[i] = *(const bf16x8*)(fA + bo + i * 1024);
        __builtin_amdgcn_s_setprio(1);
        #pragma unroll
        for (int i = 0; i < 4; ++i)
            #pragma unroll
            for (int q = 0; q < 4; ++q)
                acc[i][q] = __builtin_amdgcn_mfma_f32_16x16x32_bf16(a[i], b[q], acc[i][q], 0, 0, 0);
        __builtin_amdgcn_s_setprio(0);

        // phase 2: issue B-prefetch; A frags mh=1
        if (do_stage) {
            async16(ldB0 + sbo, pB0 + tgt * BK);
            async16(ldB1 + sbo, pB1 + tgt * BK);
        }
        #pragma unroll
        for (int i = 0; i < 4; ++i) a[i] = *(const bf16x8*)(fA + bo + (4 + i) * 1024);
        __builtin_amdgcn_s_setprio(1);
        #pragma unroll
        for (int i = 0; i < 4; ++i)
            #pragma unroll
            for (int q = 0; q < 4; ++q)
                acc[4 + i][q] = __builtin_amdgcn_mfma_f32_16x16x32_bf16(a[i], b[q], acc[4 + i][q], 0, 0, 0);
        __builtin_amdgcn_s_setprio(0);

        // checkpoint: retire next tile's staging (counted, never 0 until tail), barrier.
        if (t < NT - 3)      asm volatile("s_waitcnt vmcnt(8)" ::: "memory");
        else if (t == NT - 3) asm volatile("s_waitcnt vmcnt(4)" ::: "memory");
        else if (t == NT - 2) asm volatile("s_waitcnt vmcnt(0)" ::: "memory");
        if (t < NT - 1) {
            __builtin_amdgcn_s_barrier();
            __builtin_amdgcn_sched_barrier(0);
        }
    }

    // ---- epilogue: -s*sqrt(max(x2+w2-2*acc, eps)); direct stores.
    // C/D layout: col = lane&15 (n-side), row = (lane>>4)*4 + reg (m-side).
    // Lanes 0..15 of a store cover 16 consecutive cols -> 64 B segments.
    const float s = scales[0];
    const int colb = n0 + wn * 64 + fr;
    const int rowb = m0 + wm * 128 + fq * 4;

    float w2v[4];
    #pragma unroll
    for (int q = 0; q < 4; ++q) w2v[q] = w2[colb + q * 16];

    #pragma unroll
    for (int i = 0; i < 8; ++i) {
        float x2v[4];
        #pragma unroll
        for (int r = 0; r < 4; ++r) x2v[r] = x2[rowb + i * 16 + r];
        #pragma unroll
        for (int q = 0; q < 4; ++q) {
            if (colb + q * 16 < C_COLS) {
                float* orow = out + (size_t)(rowb + i * 16) * C_COLS + colb + q * 16;
                #pragma unroll
                for (int r = 0; r < 4; ++r) {
                    float d2 = x2v[r] + w2v[q] - 2.0f * acc[i][q][r];
                    d2 = fmaxf(d2, EPS_D2);
                    orow[(size_t)r * C_COLS] = -s * __builtin_sqrtf(d2);
                }
            }
        }
    }
}

extern "C" void kernel_launch(void* const* d_in, const int* in_sizes, int n_in,
                              void* d_out, int out_size, void* d_ws, size_t ws_size,
                              hipStream_t stream) {
    const float* x      = (const float*)d_in[0];
    const float* w      = (const float*)d_in[1];
    const float* scales = (const float*)d_in[2];
    float* out = (float*)d_out;

    char* ws = (char*)d_ws;
    __hip_bfloat16* xb = (__hip_bfloat16*)ws;                                  // 67,108,864 B
    __hip_bfloat16* wb = (__hip_bfloat16*)(ws + (size_t)B_ROWS * D_K * 2);     //  4,194,304 B
    float* x2 = (float*)(ws + (size_t)B_ROWS * D_K * 2 + (size_t)C_PAD * D_K * 2);
    float* w2 = x2 + B_ROWS;

    prep_all<<<dim3((B_ROWS + C_PAD) / 4), dim3(256), 0, stream>>>(x, w, xb, wb, x2, w2);
    dml_gemm<<<dim3((B_ROWS / BM) * (C_PAD / BN)), dim3(512), 0, stream>>>(xb, wb, x2, w2, scales, out);
}